// Round 5
// baseline (285.317 us; speedup 1.0000x reference)
//
#include <hip/hip_runtime.h>

// ---------------- problem constants ----------------
#define BATCH   8
#define LSEQ    1048576          // 1<<20
#define KCONV   500
#define TWIN    2097             // (L-K)/K + 1
#define MROWS   16776            // BATCH*TWIN
#define MPAD    16896            // 264 * 64
#define KDIM    4000             // KCONV * C_IN
#define NDIM    256              // 2 * C_OUT
#define COUT    128
#define VOCAB   257
#define VOCABP  256              // padding row of emb (zeros)

#define SPLITK  5
#define KCH     (KDIM / SPLITK)  // 800 k per split
#define PCH     (KCH / 8)        // 100 positions per split
#define NSLAB   5                // slabs per block
#define SLABP   20               // positions per slab (= 160 k = 5 BK32 iters)
#define BM      64               // m-rows per block; BN = 256 (full N)
#define AROWSH  168              // padded shorts per A-slab row (160 + 8) -> conflict-free

// ---------------- ws layout (bytes) ----------------
#define WTF_OFF   0ull
#define WTF_BYTES ((size_t)125 * 256 * 32 * 2)              // 2,048,000 (frag-major Wt)
#define EMB_OFF   (WTF_OFF + WTF_BYTES)
#define EMB_BYTES 4128ull                                   // 257*8 shorts, padded
#define CP_OFF    (EMB_OFF + EMB_BYTES)
#define CP_BYTES  ((size_t)SPLITK * NDIM * MPAD * 2)        // 43,253,760 (bf16 [kc][n][m])
#define POOL_OFF  (CP_OFF + CP_BYTES)
#define POOL_BYTES (1024ull * 4)
#define FLAG_OFF  (POOL_OFF + POOL_BYTES)

typedef __attribute__((ext_vector_type(8))) __bf16 bf16x8;
typedef __attribute__((ext_vector_type(4))) float  floatx4;

__device__ inline unsigned short f2bf(float f) {
    union { float f; unsigned u; } c; c.f = f;
    return (unsigned short)((c.u + 0x7FFFu + ((c.u >> 16) & 1u)) >> 16);
}
__device__ inline unsigned pack2(float lo, float hi) {
    return (unsigned)f2bf(lo) | ((unsigned)f2bf(hi) << 16);
}
__device__ inline float bf2f(unsigned short u) {
    return __uint_as_float((unsigned)u << 16);
}

// ---------------- kernel 1: frag-major weights + bf16 emb table + zero flag ----------------
// Wtf[kt][n][kk] = w_n[e=(kt*32+kk)&7][k=(kt*32+kk)>>3]  (kt in [0,125), kk in [0,32))
// A wave B-frag load (lane = (r16,q)) then reads contiguous 1 KB: fully coalesced.
__global__ __launch_bounds__(256) void wprep_kernel(const float* __restrict__ w1,
                                                    const float* __restrict__ w2,
                                                    const float* __restrict__ emb,
                                                    unsigned short* __restrict__ Wtf,
                                                    unsigned short* __restrict__ embbf,
                                                    unsigned int* __restrict__ flag) {
    const int n   = blockIdx.x;                        // 0..255
    const int tid = threadIdx.x;
    __shared__ float tile[KDIM];                       // 16 KB
    const float* src = (n < COUT) ? (w1 + (size_t)n * KDIM)
                                  : (w2 + (size_t)(n - COUT) * KDIM);
    for (int i = tid; i < KDIM; i += 256) tile[i] = src[i];
    __syncthreads();
    for (int i = tid; i < KDIM; i += 256) {
        int kt = i >> 5, kk = i & 31;
        Wtf[(size_t)kt * (NDIM * 32) + n * 32 + kk] = f2bf(tile[(i & 7) * KCONV + (i >> 3)]);
    }
    if (n == 0) {
        for (int i = tid; i < VOCAB * 8; i += 256) embbf[i] = f2bf(emb[i]);
        if (tid == 0) *flag = 0u;
    }
}

// ---------------- kernel 2: fused embed+GEMM, slab-staged A, register B ----------------
// Cp[kc][n][m] (bf16) = A_chunk[MPAD][800] x W_chunk^T.  Grid (264, 5), 256 thr.
// A: staged into LDS in 160-k slabs (double buffer) -> ONE barrier per 5 MFMA-iters.
//    Staging = minimal gathers: 256 threads x 5 uint4 gathers from embbf (4KB, L1).
// B: per-wave coalesced 16B/lane register loads from frag-major Wtf (L2), prefetch depth 1.
__global__ __launch_bounds__(256, 3) void gemm_kernel(const int* __restrict__ x,
                                                      const unsigned short* __restrict__ embbf,
                                                      const unsigned short* __restrict__ Wtf,
                                                      unsigned short* __restrict__ Cp) {
    __shared__ unsigned short As[2][BM * AROWSH];      // 2 x 21 KB

    const int tid  = threadIdx.x;
    const int lane = tid & 63;
    const int wv   = tid >> 6;
    const int m0   = blockIdx.x * BM;
    const int kc   = blockIdx.y;
    const int r16  = lane & 15;
    const int q    = lane >> 4;                        // k-group within BK=32

    // ---- A-staging role: thread -> (row sr, pos-phase spq) ----
    const int  sr     = tid >> 2;                      // 0..63
    const int  spq    = tid & 3;                       // 0..3
    const int  am     = m0 + sr;
    const bool avalid = (am < MROWS);
    const int  amc    = avalid ? am : 0;
    const int  ab     = amc / TWIN;
    const int  at     = amc - ab * TWIN;
    const int* xrow   = x + ((size_t)ab * LSEQ + (size_t)at * KCONV + kc * PCH + spq);
    unsigned short* sdst = (unsigned short*)As + sr * AROWSH + spq * 8;  // + buf*BM*AROWSH

    // ---- B frag offsets (shorts): lane (r16,q), frag j at n = wv*64+j*16+r16 ----
    size_t boff[4];
#pragma unroll
    for (int j = 0; j < 4; ++j)
        boff[j] = (size_t)(wv * 64 + j * 16 + r16) * 32 + q * 8;
    const unsigned short* Wkc = Wtf + (size_t)(kc * 25) * (NDIM * 32);

    floatx4 acc[4][4];
#pragma unroll
    for (int i = 0; i < 4; ++i)
#pragma unroll
        for (int j = 0; j < 4; ++j) acc[i][j] = floatx4{0.f, 0.f, 0.f, 0.f};

    // ---- prologue: stage slab 0 into buf 0 ----
    {
        int v[5];
#pragma unroll
        for (int l = 0; l < 5; ++l) v[l] = avalid ? xrow[4 * l] : VOCABP;
        uint4 g[5];
#pragma unroll
        for (int l = 0; l < 5; ++l) g[l] = *(const uint4*)(embbf + v[l] * 8);
#pragma unroll
        for (int l = 0; l < 5; ++l) *(uint4*)(sdst + 4 * l * 8) = g[l];
    }
    __syncthreads();

    int buf = 0;
    for (int s = 0; s < NSLAB; ++s) {
        // ---- stage next slab into buf^1 (gathers issued early; 5 iters to complete) ----
        if (s + 1 < NSLAB) {
            int v[5];
#pragma unroll
            for (int l = 0; l < 5; ++l) v[l] = avalid ? xrow[(s + 1) * SLABP + 4 * l] : VOCABP;
            uint4 g[5];
#pragma unroll
            for (int l = 0; l < 5; ++l) g[l] = *(const uint4*)(embbf + v[l] * 8);
            unsigned short* d = sdst + (buf ^ 1) * (BM * AROWSH);
#pragma unroll
            for (int l = 0; l < 5; ++l) *(uint4*)(d + 4 * l * 8) = g[l];
        }

        // ---- compute 5 BK=32 iterations from As[buf], B prefetched depth-1 ----
        const unsigned short* Asb = (const unsigned short*)As + buf * (BM * AROWSH);
        const unsigned short* Wts = Wkc + (size_t)(s * 5) * (NDIM * 32);
        bf16x8 bcur[4], bnxt[4], af[4];
#pragma unroll
        for (int j = 0; j < 4; ++j) bcur[j] = *(const bf16x8*)(Wts + boff[j]);
#pragma unroll
        for (int kt = 0; kt < 5; ++kt) {
            if (kt < 4) {
#pragma unroll
                for (int j = 0; j < 4; ++j)
                    bnxt[j] = *(const bf16x8*)(Wts + (size_t)(kt + 1) * (NDIM * 32) + boff[j]);
            }
#pragma unroll
            for (int i = 0; i < 4; ++i)
                af[i] = *(const bf16x8*)(Asb + (16 * i + r16) * AROWSH + (kt * 4 + q) * 8);
#pragma unroll
            for (int i = 0; i < 4; ++i)
#pragma unroll
                for (int j = 0; j < 4; ++j)
                    acc[i][j] = __builtin_amdgcn_mfma_f32_16x16x32_bf16(af[i], bcur[j], acc[i][j], 0, 0, 0);
#pragma unroll
            for (int j = 0; j < 4; ++j) bcur[j] = bnxt[j];
        }
        __syncthreads();
        buf ^= 1;
    }

    // ---- epilogue: Cp[kc][n][m] bf16; C/D layout col=lane&15, row=(lane>>4)*4+reg ----
    unsigned short* Cout = Cp + (size_t)kc * NDIM * MPAD;
#pragma unroll
    for (int i = 0; i < 4; ++i) {
        const int mb = m0 + i * 16 + q * 4;
#pragma unroll
        for (int j = 0; j < 4; ++j) {
            const int n = wv * 64 + j * 16 + r16;
            uint2 u;
            u.x = pack2(acc[i][j][0], acc[i][j][1]);
            u.y = pack2(acc[i][j][2], acc[i][j][3]);
            *(uint2*)(Cout + (size_t)n * MPAD + mb) = u;
        }
    }
}

// ---------------- kernel 3: split-sum + gate + max over t, fused dense head ----------------
__global__ __launch_bounds__(256) void gate_kernel(const unsigned short* __restrict__ Cp,
                                                   const float* __restrict__ b1,
                                                   const float* __restrict__ b2,
                                                   float* __restrict__ pool,
                                                   unsigned int* __restrict__ flag,
                                                   const float* __restrict__ wd1,
                                                   const float* __restrict__ bd1,
                                                   const float* __restrict__ wd2,
                                                   const float* __restrict__ bd2,
                                                   float* __restrict__ out) {
    const int o = blockIdx.x;                          // 0..127
    const int b = blockIdx.y;                          // 0..7
    const int t = threadIdx.x;                         // 0..255
    const float b1v = b1[o], b2v = b2[o];
    const size_t mb = (size_t)b * TWIN;
    const unsigned short* s1[SPLITK];
    const unsigned short* s2[SPLITK];
#pragma unroll
    for (int s = 0; s < SPLITK; ++s) {
        s1[s] = Cp + ((size_t)s * NDIM + o) * MPAD + mb;
        s2[s] = Cp + ((size_t)s * NDIM + o + COUT) * MPAD + mb;
    }
    float gmax = 0.0f;                                 // gated = relu*sigmoid >= 0
    for (int m = t; m < TWIN; m += 256) {              // stride-1: coalesced
        float c1 = b1v, c2 = b2v;
#pragma unroll
        for (int s = 0; s < SPLITK; ++s) {
            c1 += bf2f(s1[s][m]);
            c2 += bf2f(s2[s][m]);
        }
        float g = fmaxf(c1, 0.0f) / (1.0f + __expf(-c2));
        gmax = fmaxf(gmax, g);
    }
    __shared__ float red[256];
    red[t] = gmax;
    __syncthreads();
#pragma unroll
    for (int s = 128; s > 0; s >>= 1) {
        if (t < s) red[t] = fmaxf(red[t], red[t + s]);
        __syncthreads();
    }
    __shared__ unsigned int ticket;
    if (t == 0) {
        pool[b * COUT + o] = red[0];
        __threadfence();                               // make pool visible device-wide
        ticket = atomicAdd(flag, 1u);                  // device-scope
    }
    __syncthreads();
    if (ticket == COUT * BATCH - 1) {                  // last block: run the head
        __shared__ float hred[BATCH][COUT];
        const volatile float* pv = (const volatile float*)pool;
        if (t < COUT) {
            const int j = t;
            const float wj = wd2[j];
#pragma unroll
            for (int bb = 0; bb < BATCH; ++bb) {
                float s = bd1[j];
                for (int i = 0; i < COUT; ++i) s += pv[bb * COUT + i] * wd1[j * COUT + i];
                hred[bb][j] = fmaxf(s, 0.0f) * wj;
            }
        }
        __syncthreads();
        if (t < BATCH) {
            float s = 0.0f;
            for (int i = 0; i < COUT; ++i) s += hred[t][i];
            out[t] = 1.0f / (1.0f + expf(-(s + bd2[0])));
        }
    }
}

// ---------------- launch ----------------
extern "C" void kernel_launch(void* const* d_in, const int* in_sizes, int n_in,
                              void* d_out, int out_size, void* d_ws, size_t ws_size,
                              hipStream_t stream) {
    const int*   x   = (const int*)d_in[0];
    const float* emb = (const float*)d_in[1];
    const float* w1  = (const float*)d_in[2];
    const float* b1  = (const float*)d_in[3];
    const float* w2  = (const float*)d_in[4];
    const float* b2  = (const float*)d_in[5];
    const float* wd1 = (const float*)d_in[6];
    const float* bd1 = (const float*)d_in[7];
    const float* wd2 = (const float*)d_in[8];
    const float* bd2 = (const float*)d_in[9];
    float* out = (float*)d_out;

    unsigned short* Wtf   = (unsigned short*)((char*)d_ws + WTF_OFF);
    unsigned short* embbf = (unsigned short*)((char*)d_ws + EMB_OFF);
    unsigned short* Cp    = (unsigned short*)((char*)d_ws + CP_OFF);
    float*          pool  = (float*)((char*)d_ws + POOL_OFF);
    unsigned int*   flag  = (unsigned int*)((char*)d_ws + FLAG_OFF);

    wprep_kernel<<<dim3(NDIM), dim3(256), 0, stream>>>(w1, w2, emb, Wtf, embbf, flag);
    gemm_kernel<<<dim3(MPAD / BM, SPLITK), dim3(256), 0, stream>>>(x, embbf, Wtf, Cp);
    gate_kernel<<<dim3(COUT, BATCH), dim3(256), 0, stream>>>(Cp, b1, b2, pool, flag,
                                                             wd1, bd1, wd2, bd2, out);
}

// Round 6
// 217.420 us; speedup vs baseline: 1.3123x; 1.3123x over previous
//
#include <hip/hip_runtime.h>

// ---------------- problem constants ----------------
#define BATCH   8
#define LSEQ    1048576          // 1<<20
#define KCONV   500
#define TWIN    2097             // (L-K)/K + 1
#define MROWS   16776            // BATCH*TWIN
#define KDIM    4000             // KCONV * C_IN
#define NDIM    256              // 2 * C_OUT
#define COUT    128
#define VOCAB   257
#define VOCABP  256              // padding row of emb (zeros)

#define BM      64               // m-rows per block
#define NBLK    263              // ceil(MROWS / BM)
#define SLABP   20               // positions per slab = 160 k-elems = 5 BK32 iters
#define NSLAB   25               // 25 slabs * 160 k = 4000
#define AROWSH  168              // padded shorts per A-slab row (160 + 8)

// ---------------- ws layout (bytes) ----------------
#define WTF_OFF   0ull
#define WTF_BYTES ((size_t)125 * NDIM * 32 * 2)             // 2,048,000 (frag-major W)
#define EMB_OFF   (WTF_OFF + WTF_BYTES)
#define EMB_BYTES 4128ull                                   // 257*8 shorts, padded
#define POOL_OFF  (EMB_OFF + EMB_BYTES)                     // 1024 floats

typedef __attribute__((ext_vector_type(8))) __bf16 bf16x8;
typedef __attribute__((ext_vector_type(4))) float  floatx4;

__device__ inline unsigned short f2bf(float f) {
    union { float f; unsigned u; } c; c.f = f;
    return (unsigned short)((c.u + 0x7FFFu + ((c.u >> 16) & 1u)) >> 16);
}

// ---------------- kernel 1: frag-major weights + bf16 emb table + zero pool ----------------
// Wtf[g][n][kk] = w_n[e=(g*32+kk)&7][k=(g*32+kk)>>3]   (g in [0,125), kk in [0,32))
__global__ __launch_bounds__(256) void wprep_kernel(const float* __restrict__ w1,
                                                    const float* __restrict__ w2,
                                                    const float* __restrict__ emb,
                                                    unsigned short* __restrict__ Wtf,
                                                    unsigned short* __restrict__ embbf,
                                                    float* __restrict__ pool) {
    const int n   = blockIdx.x;                        // 0..255
    const int tid = threadIdx.x;
    __shared__ float tile[KDIM];                       // 16 KB
    const float* src = (n < COUT) ? (w1 + (size_t)n * KDIM)
                                  : (w2 + (size_t)(n - COUT) * KDIM);
    for (int i = tid; i < KDIM; i += 256) tile[i] = src[i];
    __syncthreads();
    for (int i = tid; i < KDIM; i += 256) {
        int g = i >> 5, kk = i & 31;
        Wtf[(size_t)g * (NDIM * 32) + n * 32 + kk] = f2bf(tile[(i & 7) * KCONV + (i >> 3)]);
    }
    if (n == 0) {
        for (int i = tid; i < VOCAB * 8; i += 256) embbf[i] = f2bf(emb[i]);
        if (tid < BATCH * COUT / 2) {                  // zero pool (1024 floats)
            ((float2*)pool)[tid] = float2{0.f, 0.f};
        }
    }
}

// ---------------- kernel 2: fused embed + full-K GEMM + gate + max-pool epilogue ----------------
// Grid (263), 256 thr. Each block: 64 m-rows x all 256 n, K=4000 via 25 slabs of 160k.
// Wave n-map: j in {0,1} -> n = wv*32 + j*16 + r16 (c1);  j in {2,3} -> n+128 (c2).
// => each lane holds c1 and c2 for the same o: gate + per-batch max in REGISTERS,
//    flushed via float-as-int atomicMax into pool (values >= 0, no fence needed).
__global__ __launch_bounds__(256) void gemm_kernel(const int* __restrict__ x,
                                                   const unsigned short* __restrict__ embbf,
                                                   const unsigned short* __restrict__ Wtf,
                                                   const float* __restrict__ b1,
                                                   const float* __restrict__ b2,
                                                   float* __restrict__ pool) {
    __shared__ unsigned short As[2][BM * AROWSH];      // 2 x 21 KB

    const int tid  = threadIdx.x;
    const int lane = tid & 63;
    const int wv   = tid >> 6;
    const int m0   = blockIdx.x * BM;
    const int r16  = lane & 15;
    const int q    = lane >> 4;                        // k-group within BK=32

    // ---- A-staging role: thread -> (row sr, pos-phase spq) ----
    const int  sr     = tid >> 2;                      // 0..63
    const int  spq    = tid & 3;                       // 0..3
    const int  am     = m0 + sr;
    const bool avalid = (am < MROWS);
    const int  amc    = avalid ? am : 0;
    const int  ab     = amc / TWIN;
    const int  at     = amc - ab * TWIN;
    const int* xrow   = x + ((size_t)ab * LSEQ + (size_t)at * KCONV + spq);
    unsigned short* sdst = (unsigned short*)As + sr * AROWSH + spq * 8;

    // ---- B frag offsets (shorts): n(j) = wv*32 + (j&1)*16 + r16 + (j>>1)*128 ----
    const size_t b0 = (size_t)(wv * 32 + r16) * 32 + q * 8;
    const size_t boff[4] = { b0, b0 + 16 * 32, b0 + 128 * 32, b0 + 144 * 32 };

    floatx4 acc[4][4];
#pragma unroll
    for (int i = 0; i < 4; ++i)
#pragma unroll
        for (int j = 0; j < 4; ++j) acc[i][j] = floatx4{0.f, 0.f, 0.f, 0.f};

    // ---- prologue: stage slab 0 into buf 0 ----
    {
        int v[5];
#pragma unroll
        for (int l = 0; l < 5; ++l) v[l] = avalid ? xrow[4 * l] : VOCABP;
#pragma unroll
        for (int l = 0; l < 5; ++l)
            *(uint4*)(sdst + 32 * l) = *(const uint4*)(embbf + v[l] * 8);
    }
    __syncthreads();

    int buf = 0;
    for (int s = 0; s < NSLAB; ++s) {
        // ---- stage next slab into buf^1 (issued early; 5 MFMA-iters of cover) ----
        if (s + 1 < NSLAB) {
            int v[5];
#pragma unroll
            for (int l = 0; l < 5; ++l)
                v[l] = avalid ? xrow[(s + 1) * SLABP + 4 * l] : VOCABP;
            unsigned short* d = sdst + (buf ^ 1) * (BM * AROWSH);
#pragma unroll
            for (int l = 0; l < 5; ++l)
                *(uint4*)(d + 32 * l) = *(const uint4*)(embbf + v[l] * 8);
        }

        // ---- 5 BK=32 iterations from As[buf]; B register-prefetch depth 1 ----
        const unsigned short* Asb = (const unsigned short*)As + buf * (BM * AROWSH);
        const unsigned short* Wts = Wtf + (size_t)(s * 5) * (NDIM * 32);
        bf16x8 bcur[4], bnxt[4], af[4];
#pragma unroll
        for (int j = 0; j < 4; ++j) bcur[j] = *(const bf16x8*)(Wts + boff[j]);
#pragma unroll
        for (int kt = 0; kt < 5; ++kt) {
            const bool more = (s * 5 + kt + 1 < 125);
            if (more) {
#pragma unroll
                for (int j = 0; j < 4; ++j)
                    bnxt[j] = *(const bf16x8*)(Wts + (size_t)(kt + 1) * (NDIM * 32) + boff[j]);
            }
#pragma unroll
            for (int i = 0; i < 4; ++i)
                af[i] = *(const bf16x8*)(Asb + (16 * i + r16) * AROWSH + (kt * 4 + q) * 8);
#pragma unroll
            for (int i = 0; i < 4; ++i)
#pragma unroll
                for (int j = 0; j < 4; ++j)
                    acc[i][j] = __builtin_amdgcn_mfma_f32_16x16x32_bf16(af[i], bcur[j], acc[i][j], 0, 0, 0);
#pragma unroll
            for (int j = 0; j < 4; ++j) bcur[j] = bnxt[j];
        }
        __syncthreads();
        buf ^= 1;
    }

    // ---- epilogue: gate + per-batch max in registers, atomicMax flush ----
    // C/D layout: col = lane&15 (n), row = q*4 + reg (m). Lane rows: m0 + i*16 + q*4 + rg.
#pragma unroll
    for (int j = 0; j < 2; ++j) {
        const int o   = wv * 32 + j * 16 + r16;        // 0..127
        const float b1v = b1[o], b2v = b2[o];
        float cur = 0.0f;
        int curb  = (m0 + q * 4) / TWIN;
#pragma unroll
        for (int i = 0; i < 4; ++i) {
#pragma unroll
            for (int rg = 0; rg < 4; ++rg) {
                const int row = m0 + i * 16 + q * 4 + rg;
                if (row < MROWS) {
                    const int bb = row / TWIN;
                    if (bb != curb) {
                        atomicMax((int*)&pool[curb * COUT + o], __float_as_int(cur));
                        cur = 0.0f; curb = bb;
                    }
                    const float c1 = acc[i][j][rg] + b1v;
                    const float c2 = acc[i][j + 2][rg] + b2v;
                    const float g  = fmaxf(c1, 0.0f) / (1.0f + __expf(-c2));
                    cur = fmaxf(cur, g);
                }
            }
        }
        atomicMax((int*)&pool[curb * COUT + o], __float_as_int(cur));
    }
}

// ---------------- kernel 3: dense head ----------------
__global__ __launch_bounds__(128) void head_kernel(const float* __restrict__ pool,
                                                   const float* __restrict__ wd1,
                                                   const float* __restrict__ bd1,
                                                   const float* __restrict__ wd2,
                                                   const float* __restrict__ bd2,
                                                   float* __restrict__ out) {
    __shared__ float red[BATCH][COUT];
    int j = threadIdx.x;                               // 0..127
    float wj = wd2[j];
#pragma unroll
    for (int b = 0; b < BATCH; ++b) {
        float s = bd1[j];
        for (int i = 0; i < COUT; ++i) s += pool[b * COUT + i] * wd1[j * COUT + i];
        red[b][j] = fmaxf(s, 0.0f) * wj;
    }
    __syncthreads();
    if (j < BATCH) {
        float s = 0.0f;
        for (int i = 0; i < COUT; ++i) s += red[j][i];
        out[j] = 1.0f / (1.0f + expf(-(s + bd2[0])));
    }
}

// ---------------- launch ----------------
extern "C" void kernel_launch(void* const* d_in, const int* in_sizes, int n_in,
                              void* d_out, int out_size, void* d_ws, size_t ws_size,
                              hipStream_t stream) {
    const int*   x   = (const int*)d_in[0];
    const float* emb = (const float*)d_in[1];
    const float* w1  = (const float*)d_in[2];
    const float* b1  = (const float*)d_in[3];
    const float* w2  = (const float*)d_in[4];
    const float* b2  = (const float*)d_in[5];
    const float* wd1 = (const float*)d_in[6];
    const float* bd1 = (const float*)d_in[7];
    const float* wd2 = (const float*)d_in[8];
    const float* bd2 = (const float*)d_in[9];
    float* out = (float*)d_out;

    unsigned short* Wtf   = (unsigned short*)((char*)d_ws + WTF_OFF);
    unsigned short* embbf = (unsigned short*)((char*)d_ws + EMB_OFF);
    float*          pool  = (float*)((char*)d_ws + POOL_OFF);

    wprep_kernel<<<dim3(NDIM), dim3(256), 0, stream>>>(w1, w2, emb, Wtf, embbf, pool);
    gemm_kernel<<<dim3(NBLK), dim3(256), 0, stream>>>(x, embbf, Wtf, b1, b2, pool);
    head_kernel<<<dim3(1), dim3(128), 0, stream>>>(pool, wd1, bd1, wd2, bd2, out);
}